// Round 8
// baseline (320.317 us; speedup 1.0000x reference)
//
#include <hip/hip_runtime.h>
#include <stdint.h>

typedef unsigned long long u64;

#define N_ANCH 100000
#define BATCH 8
#define NTGT 64
#define NFEAT 84
#define BLK 256
#define NWAVE (BLK / 64)
#define NBX ((N_ANCH + BLK - 1) / BLK)   // 391 blocks per batch
#define GCHUNK (NFEAT / 4)               // 21 float4 per anchor row
#define CPB (N_ANCH * GCHUNK)            // 2.1M float4 chunks per batch

// ---------------------------------------------------------------------------
// Inner loop (proven-exact R7 form), templated on FULL.
// ---------------------------------------------------------------------------
template <bool FULL>
__device__ __forceinline__ void iou_loop(
    const int tid, const int wave, const int n, const bool valid,
    const float4* __restrict__ tbox, const float* __restrict__ sarea,
    u64* __restrict__ board, const float* __restrict__ anchors, u64& bestA)
{
#pragma clang fp contract(off)
    const int nld = FULL ? n : (valid ? n : 0);
    const float4 ab = *(const float4*)(anchors + (size_t)nld * 4);
    const float ax1 = ab.x - ab.z * 0.5f;
    const float ay1 = ab.y - ab.w * 0.5f;
    const float ax2 = ab.x + ab.z * 0.5f;
    const float ay2 = ab.y + ab.w * 0.5f;
    const float areaA = (ax2 - ax1) * (ay2 - ay1);
    const u64 pn = (u64)(0xFFFFFFFFu - (uint32_t)n);     // larger = smaller n

    for (int s = 0; s < NTGT; ++s) {
        const int t = (tid + s) & (NTGT - 1);            // distinct t per lane
        const float4 tb = tbox[t];                       // ds_read_b128
        const float areaB = sarea[t];                    // staged, exact op order

        const float w = fmaxf(fminf(ax2, tb.z) - fmaxf(ax1, tb.x), 0.0f);
        const float h = fmaxf(fminf(ay2, tb.w) - fmaxf(ay1, tb.y), 0.0f);
        const float inter = w * h;
        const float iou = inter / (((areaA + areaB) - inter) + 1e-9f);  // IEEE
        const uint32_t ib = __float_as_uint(iou);        // iou>=0: bits monotone

        const u64 pa = ((u64)ib << 32) | (u64)(63 - t);  // ties -> smallest t
        bestA = pa > bestA ? pa : bestA;

        u64 c = ((u64)ib << 32) | pn;                    // ties -> smallest n
        if (!FULL) c = valid ? c : 0ull;
        atomicMax(&board[(size_t)wave * NTGT + t], c);   // native ds_max_u64
    }
}

// ---------------------------------------------------------------------------
// Kernel 1: IoU loop -> masks, per-anchor target idx (ws), per-target
// block partials (ws). No gather here (instrumentation split).
// ---------------------------------------------------------------------------
__global__ __launch_bounds__(BLK) void loop_kernel(
    const float* __restrict__ labels,    // [B, NTGT, NFEAT]
    const float* __restrict__ anchors,   // [N_ANCH, 4] cxcywh
    float* __restrict__ out_fore,        // [B, N_ANCH]
    float* __restrict__ out_back,        // [B, N_ANCH]
    int* __restrict__ ws_tgt,            // [B, N_ANCH]
    u64* __restrict__ ws_part)           // [B, NTGT, NBX]
{
#pragma clang fp contract(off)
    __shared__ float4 tbox[NTGT];
    __shared__ float sarea[NTGT];
    __shared__ u64 board[NWAVE * NTGT];

    const int b    = blockIdx.y;
    const int bx   = blockIdx.x;
    const int tid  = threadIdx.x;
    const int wave = tid >> 6;

    if (tid < NTGT) {
        const float4 box = *(const float4*)(labels + ((size_t)b * NTGT + tid) * NFEAT);
        const float x1 = box.x - box.z * 0.5f;
        const float y1 = box.y - box.w * 0.5f;
        const float x2 = box.x + box.z * 0.5f;
        const float y2 = box.y + box.w * 0.5f;
        tbox[tid] = make_float4(x1, y1, x2, y2);
        sarea[tid] = (x2 - x1) * (y2 - y1);       // numpy op order
    }
    board[tid] = 0ull;                            // NWAVE*NTGT == BLK
    __syncthreads();

    const int n = bx * BLK + tid;
    u64 bestA = 0ull;
    bool valid = true;
    if (bx != NBX - 1) {
        iou_loop<true>(tid, wave, n, true, tbox, sarea, board, anchors, bestA);
    } else {
        valid = (n < N_ANCH);
        iou_loop<false>(tid, wave, n, valid, tbox, sarea, board, anchors, bestA);
    }

    if (valid) {
        const float mi = __uint_as_float((uint32_t)(bestA >> 32));
        const int   bt = 63 - (int)(bestA & 0xFFFFFFFFull);
        const bool fore = (mi >= 0.5f);
        const bool back = (!fore) && (mi < 0.4f);
        const size_t o = (size_t)b * N_ANCH + n;
        out_fore[o] = fore ? 1.0f : 0.0f;
        out_back[o] = back ? 1.0f : 0.0f;
        ws_tgt[o] = bt;
    }
    __syncthreads();

    if (tid < NTGT) {
        const u64 m0 = board[tid];
        const u64 m1 = board[NTGT + tid];
        const u64 m2 = board[2 * NTGT + tid];
        const u64 m3 = board[3 * NTGT + tid];
        const u64 a = m0 > m1 ? m0 : m1;
        const u64 c = m2 > m3 ? m2 : m3;
        ws_part[((size_t)b * NTGT + tid) * NBX + bx] = a > c ? a : c;
    }
}

// ---------------------------------------------------------------------------
// Kernel 2: fixup (unchanged, proven).
// ---------------------------------------------------------------------------
__global__ __launch_bounds__(64) void fixup_kernel(
    const u64* __restrict__ ws_part,   // [B, NTGT, NBX]
    float* __restrict__ out_fore,
    float* __restrict__ out_back)
{
    const int bt   = blockIdx.x;
    const int lane = threadIdx.x;
    const u64* p = ws_part + (size_t)bt * NBX;

    u64 best = 0ull;
    for (int i = lane; i < NBX; i += 64) {
        const u64 v = p[i];
        best = v > best ? v : best;
    }
    for (int off = 32; off > 0; off >>= 1) {
        const u64 o = __shfl_down(best, off, 64);
        best = o > best ? o : best;
    }
    if (lane == 0) {
        const uint32_t n = 0xFFFFFFFFu - (uint32_t)(best & 0xFFFFFFFFull);
        const int b = bt >> 6;
        const size_t o = (size_t)b * N_ANCH + n;
        out_fore[o] = 1.0f;
        out_back[o] = 0.0f;
    }
}

// ---------------------------------------------------------------------------
// Kernel 3: flat gather — one thread per float4 chunk, stores march linearly
// through the 269 MB output exactly like the 6.4 TB/s fill kernel.
// out float offset = b*8.4M + 4*c  (c enumerates (n,k) row-major).
// ---------------------------------------------------------------------------
__global__ __launch_bounds__(BLK) void gather_kernel(
    const float* __restrict__ labels,   // [B, NTGT, NFEAT]
    const int* __restrict__ ws_tgt,     // [B, N_ANCH]
    float* __restrict__ out_assigned)   // [B, N_ANCH, NFEAT]
{
    const int b = blockIdx.y;
    const unsigned int c = blockIdx.x * BLK + threadIdx.x;   // [0, CPB)
    if (c < CPB) {
        const unsigned int n = c / 21u;          // compiler magic-mul
        const unsigned int k = c - n * 21u;
        const int t = ws_tgt[(size_t)b * N_ANCH + n];        // L2-cached, ~bcast
        const float4 v = *(const float4*)(labels + ((size_t)b * NTGT + t) * NFEAT
                                          + (size_t)k * 4);  // L1-resident
        *(float4*)(out_assigned + (size_t)b * (N_ANCH * NFEAT) + (size_t)c * 4) = v;
    }
}

extern "C" void kernel_launch(void* const* d_in, const int* in_sizes, int n_in,
                              void* d_out, int out_size, void* d_ws, size_t ws_size,
                              hipStream_t stream) {
    const float* labels  = (const float*)d_in[0];   // (8, 64, 84) f32
    const float* anchors = (const float*)d_in[1];   // (1, 100000, 4) f32

    float* out_fore     = (float*)d_out;                         // B*N
    float* out_back     = out_fore + (size_t)BATCH * N_ANCH;     // B*N
    float* out_assigned = out_back + (size_t)BATCH * N_ANCH;     // B*N*84

    // ws layout: ws_part [B*NTGT*NBX u64] (1.6 MB, 256-aligned), then ws_tgt
    u64* ws_part = (u64*)d_ws;
    int* ws_tgt  = (int*)((char*)d_ws + (size_t)BATCH * NTGT * NBX * sizeof(u64));

    dim3 gridA(NBX, BATCH);
    loop_kernel<<<gridA, BLK, 0, stream>>>(labels, anchors, out_fore, out_back,
                                           ws_tgt, ws_part);

    fixup_kernel<<<BATCH * NTGT, 64, 0, stream>>>(ws_part, out_fore, out_back);

    dim3 gridC((CPB + BLK - 1) / BLK, BATCH);   // (8204, 8)
    gather_kernel<<<gridC, BLK, 0, stream>>>(labels, ws_tgt, out_assigned);
}

// Round 9
// 303.951 us; speedup vs baseline: 1.0538x; 1.0538x over previous
//
#include <hip/hip_runtime.h>
#include <stdint.h>

typedef unsigned long long u64;

#define N_ANCH 100000
#define BATCH 8
#define NTGT 64
#define NFEAT 84
#define BLK 256
#define NWAVE (BLK / 64)
#define NBX ((N_ANCH + BLK - 1) / BLK)   // 391 blocks per batch
#define NBX4 (NBX * NWAVE)               // 1564 per-wave partials per (b,t)
#define GCHUNK (NFEAT / 4)               // 21 float4 per anchor row
#define WSPAN (64 * GCHUNK)              // 1344 float4 chunks per wave

// ---------------------------------------------------------------------------
// Inner loop (proven-exact R7 form), templated on FULL.
// ---------------------------------------------------------------------------
template <bool FULL>
__device__ __forceinline__ void iou_loop(
    const int tid, const int wave, const int n, const bool valid,
    const float4* __restrict__ tbox, const float* __restrict__ sarea,
    u64* __restrict__ board, const float* __restrict__ anchors, u64& bestA)
{
#pragma clang fp contract(off)
    const int nld = FULL ? n : (valid ? n : 0);
    const float4 ab = *(const float4*)(anchors + (size_t)nld * 4);
    const float ax1 = ab.x - ab.z * 0.5f;
    const float ay1 = ab.y - ab.w * 0.5f;
    const float ax2 = ab.x + ab.z * 0.5f;
    const float ay2 = ab.y + ab.w * 0.5f;
    const float areaA = (ax2 - ax1) * (ay2 - ay1);
    const u64 pn = (u64)(0xFFFFFFFFu - (uint32_t)n);     // larger = smaller n

    for (int s = 0; s < NTGT; ++s) {
        const int t = (tid + s) & (NTGT - 1);            // distinct t per lane
        const float4 tb = tbox[t];                       // ds_read_b128
        const float areaB = sarea[t];                    // staged, exact op order

        const float w = fmaxf(fminf(ax2, tb.z) - fmaxf(ax1, tb.x), 0.0f);
        const float h = fmaxf(fminf(ay2, tb.w) - fmaxf(ay1, tb.y), 0.0f);
        const float inter = w * h;
        const float iou = inter / (((areaA + areaB) - inter) + 1e-9f);  // IEEE
        const uint32_t ib = __float_as_uint(iou);        // iou>=0: bits monotone

        const u64 pa = ((u64)ib << 32) | (u64)(63 - t);  // ties -> smallest t
        bestA = pa > bestA ? pa : bestA;

        u64 c = ((u64)ib << 32) | pn;                    // ties -> smallest n
        if (!FULL) c = valid ? c : 0ull;
        // wave-private board + staggered t => uncontended native ds_max_u64
        atomicMax(&board[(size_t)wave * NTGT + t], c);
    }
}

// ---------------------------------------------------------------------------
// Fused kernel, wave-autonomous: after ONE staging barrier each wave runs
// loop -> masks -> own partial row -> own gather with no further syncs.
// ---------------------------------------------------------------------------
__global__ __launch_bounds__(BLK) void fused_kernel(
    const float* __restrict__ labels,    // [B, NTGT, NFEAT]
    const float* __restrict__ anchors,   // [N_ANCH, 4] cxcywh
    float* __restrict__ out_fore,        // [B, N_ANCH]
    float* __restrict__ out_back,        // [B, N_ANCH]
    float* __restrict__ out_assigned,    // [B, N_ANCH, NFEAT]
    u64* __restrict__ ws_part)           // [B, NBX4, NTGT]
{
#pragma clang fp contract(off)
    __shared__ float4 tbox[NTGT];
    __shared__ float sarea[NTGT];
    __shared__ u64 board[NWAVE * NTGT];

    const int b    = blockIdx.y;
    const int bx   = blockIdx.x;
    const int tid  = threadIdx.x;
    const int wave = tid >> 6;
    const int lane = tid & 63;

    if (tid < NTGT) {
        const float4 box = *(const float4*)(labels + ((size_t)b * NTGT + tid) * NFEAT);
        const float x1 = box.x - box.z * 0.5f;
        const float y1 = box.y - box.w * 0.5f;
        const float x2 = box.x + box.z * 0.5f;
        const float y2 = box.y + box.w * 0.5f;
        tbox[tid] = make_float4(x1, y1, x2, y2);
        sarea[tid] = (x2 - x1) * (y2 - y1);       // numpy op order
    }
    board[tid] = 0ull;        // board[wave][lane]: each wave zeroes its own slice
    __syncthreads();          // the ONLY block-wide barrier

    const int n = bx * BLK + tid;
    u64 bestA = 0ull;
    bool valid = true;
    if (bx != NBX - 1) {
        iou_loop<true>(tid, wave, n, true, tbox, sarea, board, anchors, bestA);
    } else {
        valid = (n < N_ANCH);
        iou_loop<false>(tid, wave, n, valid, tbox, sarea, board, anchors, bestA);
    }

    int bt = 0;
    if (valid) {
        const float mi = __uint_as_float((uint32_t)(bestA >> 32));
        bt = 63 - (int)(bestA & 0xFFFFFFFFull);
        const bool fore = (mi >= 0.5f);
        const bool back = (!fore) && (mi < 0.4f);
        const size_t o = (size_t)b * N_ANCH + n;
        out_fore[o] = fore ? 1.0f : 0.0f;
        out_back[o] = back ? 1.0f : 0.0f;
    }

    // own wave's partial row -> global (lane-contiguous, coalesced 512B);
    // same-wave ds ordering guarantees the board is complete.
    const int blk4 = bx * NWAVE + wave;
    ws_part[((size_t)b * NBX4 + blk4) * NTGT + lane] = board[wave * NTGT + lane];

    // wave-local gather: anchors [bx*256 + wave*64, +64); target idx pulled
    // from the producing lane via shfl (no LDS, no barrier).
    const float* lab_b = labels + (size_t)b * NTGT * NFEAT;
    const int wbase = bx * BLK + wave * 64;
    float* out_w = out_assigned + ((size_t)b * N_ANCH + wbase) * NFEAT;
    for (int j = lane; j < WSPAN; j += 64) {             // 21 iterations
        const int nl = j / GCHUNK;                       // local anchor 0..63
        const int k  = j - nl * GCHUNK;
        const int t  = __shfl(bt, nl, 64);
        if (wbase + nl < N_ANCH) {
            const float4 v = *(const float4*)(lab_b + (size_t)t * NFEAT + k * 4);
            *(float4*)(out_w + (size_t)nl * NFEAT + (size_t)k * 4) = v;
        }
    }
}

// ---------------------------------------------------------------------------
// Fixup: one wave per (b,t); reduce NBX4 partials; scatter fore=1/back=0 at
// the best anchor (idempotent, replicates .at[].set + back-mask update).
// ---------------------------------------------------------------------------
__global__ __launch_bounds__(64) void fixup_kernel(
    const u64* __restrict__ ws_part,   // [B, NBX4, NTGT]
    float* __restrict__ out_fore,
    float* __restrict__ out_back)
{
    const int bt_i = blockIdx.x;     // 0..B*NTGT-1
    const int b    = bt_i >> 6;
    const int t    = bt_i & 63;
    const int lane = threadIdx.x;

    u64 best = 0ull;
    for (int i = lane; i < NBX4; i += 64) {              // 25 strided rounds (L2)
        const u64 v = ws_part[((size_t)b * NBX4 + i) * NTGT + t];
        best = v > best ? v : best;
    }
    for (int off = 32; off > 0; off >>= 1) {
        const u64 o = __shfl_down(best, off, 64);
        best = o > best ? o : best;
    }
    if (lane == 0) {
        const uint32_t n = 0xFFFFFFFFu - (uint32_t)(best & 0xFFFFFFFFull);
        const size_t o = (size_t)b * N_ANCH + n;
        out_fore[o] = 1.0f;
        out_back[o] = 0.0f;
    }
}

extern "C" void kernel_launch(void* const* d_in, const int* in_sizes, int n_in,
                              void* d_out, int out_size, void* d_ws, size_t ws_size,
                              hipStream_t stream) {
    const float* labels  = (const float*)d_in[0];   // (8, 64, 84) f32
    const float* anchors = (const float*)d_in[1];   // (1, 100000, 4) f32

    float* out_fore     = (float*)d_out;                         // B*N
    float* out_back     = out_fore + (size_t)BATCH * N_ANCH;     // B*N
    float* out_assigned = out_back + (size_t)BATCH * N_ANCH;     // B*N*84

    u64* ws_part = (u64*)d_ws;                       // B*NBX4*NTGT u64 = 6.4 MB

    dim3 gridA(NBX, BATCH);
    fused_kernel<<<gridA, BLK, 0, stream>>>(labels, anchors, out_fore, out_back,
                                            out_assigned, ws_part);

    fixup_kernel<<<BATCH * NTGT, 64, 0, stream>>>(ws_part, out_fore, out_back);
}